// Round 7
// baseline (906.610 us; speedup 1.0000x reference)
//
#include <hip/hip_runtime.h>

#define NUSERS 100000
#define NITEMS 50000
#define NNODES (NUSERS + NITEMS)
#define DIM 64
#define NEDGE 2000000
#define NI4 (NNODES / 4)            // 37500 int4 count-groups
#define SCAN_B ((NI4 + 255) / 256)  // 147 blocks
#define FT_ROWS 128                 // final-kernel tile rows
#define FT_BLOCKS ((NNODES + FT_ROWS - 1) / FT_ROWS)   // 1172

#define NBC 256                     // coarse buckets
#define BCH 586                     // nodes per bucket (256*586 >= 150000)
#define C1_EPT 12                   // edges per thread in C1
#define C1_CHUNK (C1_EPT * 256)     // 3072 edges per block
#define C1_BLOCKS ((NEDGE + C1_CHUNK - 1) / C1_CHUNK)  // 652
#define C1_DEPTH 24                 // bin capacity (mean fill = 12)
#define C1_STRIDE 25                // odd stride in int2 units -> bank spread

// ---------------------------------------------------------------------------
// init: buf0 = concat(emb_users, emb_items); also write the two
// pass-through output copies. float4 per thread.
// ---------------------------------------------------------------------------
__global__ void init_kernel(const float* __restrict__ eu, const float* __restrict__ eit,
                            float* __restrict__ buf0, float* __restrict__ out) {
    long i = (long)blockIdx.x * blockDim.x + threadIdx.x;      // float4 index
    const long total = (long)NNODES * DIM / 4;
    if (i >= total) return;
    const long ue = (long)NUSERS * DIM / 4;
    float4 v;
    if (i < ue) {
        v = ((const float4*)eu)[i];
        ((float4*)(out + (long)NUSERS * DIM))[i] = v;                          // users copy
    } else {
        long j = i - ue;
        v = ((const float4*)eit)[j];
        ((float4*)(out + (long)2 * NUSERS * DIM + (long)NITEMS * DIM))[j] = v; // items copy
    }
    ((float4*)buf0)[i] = v;
}

// ---------------------------------------------------------------------------
// CSR build step 1: histogram of dst. counts must be pre-zeroed.
// ---------------------------------------------------------------------------
__global__ void hist_kernel(const int* __restrict__ eidx, int* __restrict__ counts) {
    int e = blockIdx.x * blockDim.x + threadIdx.x;
    if (e < NEDGE) atomicAdd(&counts[eidx[NEDGE + e]], 1);
}

// ---------------------------------------------------------------------------
// CSR build step 2a: per-block sums (1024 counts per block via int4).
// ---------------------------------------------------------------------------
__global__ void blk_sum_kernel(const int* __restrict__ counts, int* __restrict__ blk_sums) {
    __shared__ int lds[256];
    int t = threadIdx.x;
    int i4 = blockIdx.x * 256 + t;
    int s = 0;
    if (i4 < NI4) {
        int4 c = ((const int4*)counts)[i4];
        s = c.x + c.y + c.z + c.w;
    }
    lds[t] = s;
    __syncthreads();
    for (int d = 128; d > 0; d >>= 1) {
        if (t < d) lds[t] += lds[t + d];
        __syncthreads();
    }
    if (t == 0) blk_sums[blockIdx.x] = lds[0];
}

// ---------------------------------------------------------------------------
// CSR build step 2b: exclusive scan of the SCAN_B block sums (single block).
// ---------------------------------------------------------------------------
__global__ void blk_scan_kernel(const int* __restrict__ blk_sums, int* __restrict__ blk_off) {
    __shared__ int lds[256];
    int t = threadIdx.x;
    int v = (t < SCAN_B) ? blk_sums[t] : 0;
    lds[t] = v;
    __syncthreads();
    for (int d = 1; d < 256; d <<= 1) {
        int u = (t >= d) ? lds[t - d] : 0;
        __syncthreads();
        lds[t] += u;
        __syncthreads();
    }
    if (t < SCAN_B) blk_off[t] = lds[t] - v;   // exclusive
}

// ---------------------------------------------------------------------------
// CSR build step 2c: local exclusive scan + block offset -> row_start.
// ---------------------------------------------------------------------------
__global__ void scan_apply_kernel(const int* __restrict__ counts, const int* __restrict__ blk_off,
                                  int* __restrict__ row_start) {
    __shared__ int lds[256];
    int t = threadIdx.x;
    int i4 = blockIdx.x * 256 + t;
    int4 c = make_int4(0, 0, 0, 0);
    if (i4 < NI4) c = ((const int4*)counts)[i4];
    int tsum = c.x + c.y + c.z + c.w;
    lds[t] = tsum;
    __syncthreads();
    for (int d = 1; d < 256; d <<= 1) {
        int u = (t >= d) ? lds[t - d] : 0;
        __syncthreads();
        lds[t] += u;
        __syncthreads();
    }
    if (i4 < NI4) {
        int base = blk_off[blockIdx.x] + lds[t] - tsum;   // exclusive across chunk
        int4 r;
        r.x = base;
        r.y = base + c.x;
        r.z = r.y + c.y;
        r.w = r.z + c.z;
        ((int4*)row_start)[i4] = r;
    }
    if (blockIdx.x == 0 && t == 0) row_start[NNODES] = NEDGE;
}

// ---------------------------------------------------------------------------
// gcur init: coarse-bucket write cursors = row_start at bucket boundaries.
// ---------------------------------------------------------------------------
__global__ void gcur_init_kernel(const int* __restrict__ row_start, int* __restrict__ gcur) {
    int b = threadIdx.x;
    if (b < NBC) {
        int n0 = b * BCH; if (n0 > NNODES) n0 = NNODES;
        gcur[b] = row_start[n0];
    }
}

// ---------------------------------------------------------------------------
// C1: bin edges into 256 coarse dst-buckets via LDS staging; flush bins as
// contiguous bursts (one atomicAdd per bin per block). Record packs
// (dloc<<18 | src, w) in 8 B; dloc < 586 < 2^10, src < 150000 < 2^18.
// ---------------------------------------------------------------------------
__global__ __launch_bounds__(256)
void coarse_bin_kernel(const int* __restrict__ eidx, const float* __restrict__ ew,
                       int* __restrict__ gcur, int2* __restrict__ edge_coarse) {
    __shared__ int2 bins[NBC * C1_STRIDE];   // 51.2 KB
    __shared__ int bcnt[NBC];
    int t = threadIdx.x;
    for (int i = t; i < NBC; i += 256) bcnt[i] = 0;
    __syncthreads();

    long base = (long)blockIdx.x * C1_CHUNK;
#pragma unroll
    for (int k = 0; k < C1_EPT; ++k) {
        long e = base + (long)k * 256 + t;
        if (e < NEDGE) {
            int d = eidx[NEDGE + e];
            int s = eidx[e];
            float w = ew[e];
            int b = d / BCH;                      // magic-mul division
            int dloc = d - b * BCH;
            int2 rec;
            rec.x = (dloc << 18) | s;
            rec.y = __float_as_int(w);
            int slot = atomicAdd(&bcnt[b], 1);
            if (slot < C1_DEPTH) {
                bins[b * C1_STRIDE + slot] = rec;
            } else {                              // rare overflow: direct store
                int pos = atomicAdd(&gcur[b], 1);
                edge_coarse[pos] = rec;
            }
        }
    }
    __syncthreads();

    // flush: wave wv handles buckets [wv*64, wv*64+64)
    int lane = t & 63, wv = t >> 6;
    for (int bb = 0; bb < 64; ++bb) {
        int b = wv * 64 + bb;
        int c = bcnt[b]; if (c > C1_DEPTH) c = C1_DEPTH;
        int basep = 0;
        if (lane == 0 && c > 0) basep = atomicAdd(&gcur[b], c);
        basep = __shfl(basep, 0, 64);
        if (lane < c) edge_coarse[basep + lane] = bins[b * C1_STRIDE + lane];
    }
}

// ---------------------------------------------------------------------------
// C2: one block per coarse bucket; LDS per-node cursors (init from row_start);
// scatter records to exact CSR positions. All stores land in this block's
// private ~62 KB region -> full-line writebacks, no cross-XCD false sharing.
// ---------------------------------------------------------------------------
__global__ __launch_bounds__(256)
void refine_kernel(const int* __restrict__ row_start, const int2* __restrict__ edge_coarse,
                   int2* __restrict__ edge_packed) {
    __shared__ int lcur[BCH];
    int b = blockIdx.x;
    int n0 = b * BCH;
    int n1 = n0 + BCH; if (n1 > NNODES) n1 = NNODES;
    int nn = n1 - n0;
    int t = threadIdx.x;
    for (int i = t; i < nn; i += 256) lcur[i] = row_start[n0 + i];
    __syncthreads();
    int rbeg = row_start[n0], rend = row_start[n1];
    for (int j = rbeg + t; j < rend; j += 256) {
        int2 rec = edge_coarse[j];
        int dloc = ((unsigned)rec.x) >> 18;
        int src = rec.x & 0x3FFFF;
        int pos = atomicAdd(&lcur[dloc], 1);
        int2 o; o.x = src; o.y = rec.y;
        edge_packed[pos] = o;
    }
}

// ---------------------------------------------------------------------------
// pull: one wave per dst node, lane = dim. No atomics; fused ReLU.
// Packed 8B edge records; 4-wide unroll, 2 independent accumulators.
// ---------------------------------------------------------------------------
__global__ void pull_kernel(const int* __restrict__ row_start,
                            const int2* __restrict__ edge_packed,
                            const float* __restrict__ in_emb,
                            float* __restrict__ out_emb) {
    int lane = threadIdx.x & 63;
    int n = (int)((blockIdx.x * (long)blockDim.x + threadIdx.x) >> 6);  // node = wave id
    if (n >= NNODES) return;
    int b = row_start[n];
    int e2 = row_start[n + 1];
    float sa = 0.f, sb = 0.f;
    int i = b;
    for (; i + 3 < e2; i += 4) {
        int2 r0 = edge_packed[i],     r1 = edge_packed[i + 1];
        int2 r2 = edge_packed[i + 2], r3 = edge_packed[i + 3];
        float v0 = in_emb[(long)r0.x * DIM + lane];
        float v1 = in_emb[(long)r1.x * DIM + lane];
        float v2 = in_emb[(long)r2.x * DIM + lane];
        float v3 = in_emb[(long)r3.x * DIM + lane];
        sa = fmaf(__int_as_float(r0.y), v0, sa);
        sb = fmaf(__int_as_float(r1.y), v1, sb);
        sa = fmaf(__int_as_float(r2.y), v2, sa);
        sb = fmaf(__int_as_float(r3.y), v3, sb);
    }
    for (; i < e2; ++i) {
        int2 r = edge_packed[i];
        sa = fmaf(__int_as_float(r.y), in_emb[(long)r.x * DIM + lane], sa);
    }
    out_emb[(long)n * DIM + lane] = fmaxf(sa + sb, 0.f);
}

// ---------------------------------------------------------------------------
// epilogue GEMM, tile-staged (see R5 notes).
// ---------------------------------------------------------------------------
__global__ __launch_bounds__(256)
void final_kernel(const float* __restrict__ e0, const float* __restrict__ e1,
                  const float* __restrict__ e2, const float* __restrict__ W,
                  const float* __restrict__ bias, float* __restrict__ out) {
    __shared__ float4 As4[FT_ROWS * 16];                 // 32 KB
    const int t = threadIdx.x;
    const int lane = t & 63;
    const int wv = t >> 6;
    const long R0 = (long)blockIdx.x * FT_ROWS;

    float wreg[64];
#pragma unroll
    for (int k = 0; k < 16; ++k) {
        float4 wq = ((const float4*)(W + (long)lane * 64))[k];
        wreg[4 * k + 0] = wq.x; wreg[4 * k + 1] = wq.y;
        wreg[4 * k + 2] = wq.z; wreg[4 * k + 3] = wq.w;
    }
    float bj = bias[lane];

    const float4* g0 = (const float4*)(e0 + R0 * DIM);
    const float4* g1 = (const float4*)(e1 + R0 * DIM);
    const float4* g2 = (const float4*)(e2 + R0 * DIM);
#pragma unroll
    for (int it = 0; it < 8; ++it) {
        int idx = it * 256 + t;                          // float4 index in tile
        if (R0 + (idx >> 4) < NNODES) {
            float4 v0 = g0[idx], v1 = g1[idx], v2 = g2[idx];
            float4 s;
            s.x = v0.x + v1.x + v2.x; s.y = v0.y + v1.y + v2.y;
            s.z = v0.z + v1.z + v2.z; s.w = v0.w + v1.w + v2.w;
            As4[idx] = s;
        }
    }
    __syncthreads();

#pragma unroll 4
    for (int r = 0; r < 32; ++r) {
        int tr = wv * 32 + r;
        long row = R0 + tr;
        if (row >= NNODES) break;                        // wave-uniform
        const float4* a = As4 + tr * 16;
        float s0 = 0.f, s1 = 0.f;
#pragma unroll
        for (int k = 0; k < 16; ++k) {
            float4 v = a[k];                             // LDS broadcast
            s0 = fmaf(v.x, wreg[4 * k + 0], s0);
            s1 = fmaf(v.y, wreg[4 * k + 1], s1);
            s0 = fmaf(v.z, wreg[4 * k + 2], s0);
            s1 = fmaf(v.w, wreg[4 * k + 3], s1);
        }
        float val = fmaf(s0 + s1, (1.0f / 3.0f), bj);
        long o = (row < NUSERS) ? row * DIM
                                : (long)2 * NUSERS * DIM + (row - NUSERS) * DIM;
        out[o + lane] = val;
    }
}

extern "C" void kernel_launch(void* const* d_in, const int* in_sizes, int n_in,
                              void* d_out, int out_size, void* d_ws, size_t ws_size,
                              hipStream_t stream) {
    const int*   eidx = (const int*)d_in[0];     // (2, E) int
    const float* ew   = (const float*)d_in[1];   // (E,)
    const float* eu   = (const float*)d_in[2];   // (NUSERS, 64)
    const float* eit  = (const float*)d_in[3];   // (NITEMS, 64)
    const float* W    = (const float*)d_in[4];   // (64, 64)
    const float* bias = (const float*)d_in[5];   // (64,)
    float* out = (float*)d_out;

    const size_t nfeat = (size_t)NNODES * DIM;   // 9.6M floats
    float* buf0 = (float*)d_ws;                  // emb_0 (input concat)
    float* buf1 = buf0 + nfeat;                  // emb_1
    float* buf2 = buf1 + nfeat;                  // emb_2
    int*   counts     = (int*)(buf2 + nfeat);    // NNODES
    int*   row_start  = counts + NNODES;         // NNODES+1 (+3 pad)
    int*   gcur       = row_start + NNODES + 4;  // NBC
    int*   blk_sums   = gcur + NBC;              // SCAN_B
    int*   blk_off    = blk_sums + SCAN_B;       // SCAN_B
    int2*  edge_packed = (int2*)(((uintptr_t)(blk_off + SCAN_B) + 15) & ~(uintptr_t)15);
    // edge_coarse (16 MB) lives in d_out's emb_users_final region (25.6 MB),
    // which final_kernel fully rewrites at the end.
    int2*  edge_coarse = (int2*)out;

    const int tpb = 256;
    const long nv4 = (long)NNODES * DIM / 4;
    const int ewBlocks = (int)((nv4 + tpb - 1) / tpb);          // 9375
    const int edgeBlocks = (NEDGE + tpb - 1) / tpb;             // 7813
    const int nodeWaveBlocks = (NNODES * 64 + tpb - 1) / tpb;   // 37500

    hipMemsetAsync(counts, 0, NNODES * sizeof(int), stream);

    init_kernel<<<ewBlocks, tpb, 0, stream>>>(eu, eit, buf0, out);

    // Build row_start (hist + parallel 3-phase scan)
    hist_kernel<<<edgeBlocks, tpb, 0, stream>>>(eidx, counts);
    blk_sum_kernel<<<SCAN_B, 256, 0, stream>>>(counts, blk_sums);
    blk_scan_kernel<<<1, 256, 0, stream>>>(blk_sums, blk_off);
    scan_apply_kernel<<<SCAN_B, 256, 0, stream>>>(counts, blk_off, row_start);

    // Two-phase binned counting sort of edges by dst
    gcur_init_kernel<<<1, 256, 0, stream>>>(row_start, gcur);
    coarse_bin_kernel<<<C1_BLOCKS, 256, 0, stream>>>(eidx, ew, gcur, edge_coarse);
    refine_kernel<<<NBC, 256, 0, stream>>>(row_start, edge_coarse, edge_packed);

    // layer 1: buf0 -> buf1 (fused relu)
    pull_kernel<<<nodeWaveBlocks, tpb, 0, stream>>>(row_start, edge_packed, buf0, buf1);
    // layer 2: buf1 -> buf2
    pull_kernel<<<nodeWaveBlocks, tpb, 0, stream>>>(row_start, edge_packed, buf1, buf2);

    // epilogue GEMM (sums the three layer embeddings on the fly)
    final_kernel<<<FT_BLOCKS, tpb, 0, stream>>>(buf0, buf1, buf2, W, bias, out);
}